// Round 7
// baseline (173.981 us; speedup 1.0000x reference)
//
#include <hip/hip_runtime.h>

// ============================================================================
// einsum('bcshw,ijkl->bklhw') has no shared labels => full factorization:
//   out[b, kl, hw] = S_x[b,hw] * S_C[kl]
//   S_x[b,h,w] = sum_{p1,p2,ch} x[b, p1*8+h, p2*8+w, ch]
//   S_C[kl]    = sum over 3072 rows of C viewed as [3072][1024]
//
// Round-7: occupancy attack on the x-stream. K1's 113 MB read has run at
// ~2.6 TB/s in every structure (R2-R6: 42-50 us) at ~12 waves/CU; the only
// change that ever moved it was more in-flight loads (R6, -6.5 us). Now:
// 8 blocks/CU (24 waves/CU) via __launch_bounds__(192,6) -- each (b,h)
// class split into 2 half-blocks of 16 rows, one f4 accumulator each
// (~30 VGPR << 85 cap), halves written to disjoint xh[b][h][half][8].
// Plain loads on x (keep LLC residency); nt stores on out (don't evict x).
//
//   K1 blocks 0..95    : C column partials (32 rows each) -> cpart[96][1024]
//      blocks 96..2143 : x half-class sums -> xh[128][8][2][8]
//   K2 collapse_C (6 blocks): cpart -> scf[1024]
//   K3 expand_out: sums the two halves + outer-product, nt float4 stores.
// ============================================================================

typedef float nf4 __attribute__((ext_vector_type(4)));

__global__ __launch_bounds__(192, 6) void reduce_partials(
    const float4* __restrict__ x4,    // [128*256 rows][192 f4]
    const float4* __restrict__ C4,    // [3072 rows][256 f4]
    float*  __restrict__ cpart,       // [96][1024]
    float*  __restrict__ xh)          // [128][8][2][8] = 16384 floats
{
    const int t   = threadIdx.x;
    const int blk = blockIdx.x;

    if (blk < 96) {
        // ---- C partial: rows blk*32 .. +32, coalesced f4 column sums ----
        const size_t r0 = (size_t)blk * 32;
        for (int c4 = t; c4 < 256; c4 += 192) {
            const float4* p = C4 + r0 * 256 + c4;
            float ax = 0, ay = 0, az = 0, aw = 0;
            float bx = 0, by = 0, bz = 0, bw = 0;
#pragma unroll
            for (int r = 0; r < 32; r += 2) {
                float4 v0 = p[0];
                float4 v1 = p[256];
                ax += v0.x; ay += v0.y; az += v0.z; aw += v0.w;
                bx += v1.x; by += v1.y; bz += v1.z; bw += v1.w;
                p += 512;
            }
            float4 s;
            s.x = ax + bx; s.y = ay + by; s.z = az + bz; s.w = aw + bw;
            ((float4*)cpart)[blk * 256 + c4] = s;
        }
        return;
    }

    // ---- x half-class sum: image b, h-class h, rows h+128*half+8j, j<16 ---
    // Thread t reads f4 #t of each row (floats 4t..4t+3); component e
    // accumulates fixed class m = (4t+e) mod 24 within fixed h.
    const int task = blk - 96;            // [0,2048)
    const int b    = task >> 4;
    const int rem  = task & 15;
    const int h    = rem >> 1;
    const int half = rem & 1;
    const float4* base = x4 + ((size_t)b * 256 + h + 128 * half) * 192 + t;

    nf4 acc = (nf4)(0.f);
#pragma unroll
    for (int j = 0; j < 16; ++j) {        // 16 independent loads, tiny state
        const float4 v = base[(size_t)j * 8 * 192];
        acc.x += v.x; acc.y += v.y; acc.z += v.z; acc.w += v.w;
    }

    // Epilogue (verified R6): 192 f4 -> 24 (w,c)-classes -> 8 w-sums.
    __shared__ float4 arr[192];
    __shared__ float4 arr2[48];
    __shared__ float  cls[24];

    arr[t].x = acc.x; arr[t].y = acc.y; arr[t].z = acc.z; arr[t].w = acc.w;
    __syncthreads();

    if (t < 48) {      // fold stride-48 groups: 192 floats == 0 mod 24
        float4 a0 = arr[t], a1 = arr[t + 48], a2 = arr[t + 96], a3 = arr[t + 144];
        float4 s;
        s.x = a0.x + a1.x + a2.x + a3.x;
        s.y = a0.y + a1.y + a2.y + a3.y;
        s.z = a0.z + a1.z + a2.z + a3.z;
        s.w = a0.w + a1.w + a2.w + a3.w;
        arr2[t] = s;
    }
    __syncthreads();

    if (t < 6) {       // fold stride-6 groups: 24 floats == 0 mod 24
        float4 s; s.x = s.y = s.z = s.w = 0.f;
#pragma unroll
        for (int g = 0; g < 8; ++g) {
            float4 v = arr2[t + 6 * g];
            s.x += v.x; s.y += v.y; s.z += v.z; s.w += v.w;
        }
        cls[4 * t + 0] = s.x;
        cls[4 * t + 1] = s.y;
        cls[4 * t + 2] = s.z;
        cls[4 * t + 3] = s.w;
    }
    __syncthreads();

    if (t < 8) {       // class m = 3w + c: sum channels -> half-sum for w=t
        xh[task * 8 + t] = cls[3 * t] + cls[3 * t + 1] + cls[3 * t + 2];
    }
}

// K2: collapse C partials once. 6 blocks x 192 threads cover 1024 cols.
__global__ __launch_bounds__(192) void collapse_C(
    const float* __restrict__ cpart,   // [96][1024]
    float* __restrict__ scf)           // [1024]
{
    const int col = blockIdx.x * 192 + threadIdx.x;
    if (col < 1024) {
        float s = 0.f;
#pragma unroll 8
        for (int g = 0; g < 96; ++g) s += cpart[g * 1024 + col];
        scf[col] = s;
    }
}

// K3: pure expand. grid (8, 128): block = (kl-chunk of 128, image b).
// Sums the two x-halves, then 2048 nontemporal float4 stores per block.
__global__ __launch_bounds__(256) void expand_out(
    const float* __restrict__ xh,     // [128][8][2][8]
    const float* __restrict__ scf,    // [1024]
    float4* __restrict__ out4)        // [128][1024][16]
{
    const int t   = threadIdx.x;
    const int klc = blockIdx.x;   // [0,8)
    const int b   = blockIdx.y;   // [0,128)

    __shared__ float sxs[64];     // S_x[b][hw]
    __shared__ float scl[128];    // sC[klc*128 .. +128]

    if (t < 64) {
        const float* p = xh + b * 128 + (t >> 3) * 16 + (t & 7);
        sxs[t] = p[0] + p[8];     // half 0 + half 1
    } else if (t < 192) {
        scl[t - 64] = scf[klc * 128 + (t - 64)];
    }
    __syncthreads();

    float4* ob = out4 + (size_t)b * 16384 + (size_t)klc * 2048;
#pragma unroll
    for (int k = 0; k < 8; ++k) {
        const int idx = k * 256 + t;                     // [0,2048)
        const float4 v = ((const float4*)sxs)[idx & 15]; // LDS broadcast
        const float  s = scl[idx >> 4];
        nf4 r;
        r.x = v.x * s; r.y = v.y * s; r.z = v.z * s; r.w = v.w * s;
        __builtin_nontemporal_store(r, (nf4*)&ob[idx]);
    }
}

extern "C" void kernel_launch(void* const* d_in, const int* in_sizes, int n_in,
                              void* d_out, int out_size, void* d_ws, size_t ws_size,
                              hipStream_t stream) {
    const float4* x4 = (const float4*)d_in[0];   // 128*256*256*3 floats
    const float4* C4 = (const float4*)d_in[1];   // 3072*1024 floats

    float* cpart = (float*)d_ws;                  // 96*1024 floats
    float* xh    = cpart + 96 * 1024;             // 16384 floats
    float* scf   = xh + 16384;                    // 1024 floats

    reduce_partials<<<dim3(96 + 2048), 192, 0, stream>>>(x4, C4, cpart, xh);
    collapse_C<<<dim3(6),              192, 0, stream>>>(cpart, scf);
    expand_out<<<dim3(8, 128),         256, 0, stream>>>(xh, scf, (float4*)d_out);
}

// Round 8
// 166.482 us; speedup vs baseline: 1.0450x; 1.0450x over previous
//
#include <hip/hip_runtime.h>

// ============================================================================
// einsum('bcshw,ijkl->bklhw') has no shared labels => full factorization:
//   out[b, kl, hw] = S_x[b,hw] * S_C[kl]
//   S_x[b,h,w] = sum_{p1,p2,ch} x[b, p1*8+h, p2*8+w, ch]
//   S_C[kl]    = sum over 3072 rows of C viewed as [3072][1024]
//
// FINAL (= Round-6 best, 167.7 us measured). Budget: 118.5 us harness poison
// fills (2 x 384 MB, immovable) + ~42.5 us K1 (x-read pinned at ~2.6 TB/s by
// the degraded read path — harness's own rocclr copyBuffer reads at 826 GB/s;
// 6 structural variants all landed 2.3-2.9 TB/s) + ~6.5 us K2/K3 (at write
// floor). R7's occupancy-doubling A/B regressed (-6.3 us): depth > occupancy.
//
//   K1 blocks 0..1023   : x class-sums -> sxf[128][64] directly
//      blocks 1024..1119: C column partials (32 rows each) -> cpart[96][1024]
//   K2 collapse_C (6 blocks): cpart -> scf[1024]
//   K3 expand_out: pure outer-product expand, nontemporal float4 stores.
// ============================================================================

typedef float nf4 __attribute__((ext_vector_type(4)));

__global__ __launch_bounds__(192, 3) void reduce_partials(
    const float4* __restrict__ x4,    // [128*256 rows][192 f4]
    const float4* __restrict__ C4,    // [3072 rows][256 f4]
    float*  __restrict__ cpart,       // [96][1024]
    float*  __restrict__ sxf)         // [128][64]
{
    const int t   = threadIdx.x;
    const int blk = blockIdx.x;

    if (blk >= 1024) {
        // ---- C partial: rows cb*32 .. +32, coalesced f4 column sums ----
        const int cb = blk - 1024;
        const size_t r0 = (size_t)cb * 32;
        for (int c4 = t; c4 < 256; c4 += 192) {
            const float4* p = C4 + r0 * 256 + c4;
            float ax = 0, ay = 0, az = 0, aw = 0;
            float bx = 0, by = 0, bz = 0, bw = 0;
#pragma unroll
            for (int r = 0; r < 32; r += 2) {
                float4 v0 = p[0];
                float4 v1 = p[256];
                ax += v0.x; ay += v0.y; az += v0.z; aw += v0.w;
                bx += v1.x; by += v1.y; bz += v1.z; bw += v1.w;
                p += 512;
            }
            float4 s;
            s.x = ax + bx; s.y = ay + by; s.z = az + bz; s.w = aw + bw;
            ((float4*)cpart)[cb * 256 + c4] = s;
        }
        return;
    }

    // ---- x class-sum: image b, h-class h, rows {h+8j}, j=0..31 ----
    // Thread t reads f4 #t of each row (floats 4t..4t+3). Single f4 acc:
    // component e accumulates fixed class m = (4t+e) mod 24 within fixed h.
    const int b = blk >> 3;
    const int h = blk & 7;
    const nf4* base = (const nf4*)(x4 + ((size_t)b * 256 + h) * 192 + t);

    nf4 acc = (nf4)(0.f);
#pragma unroll
    for (int j = 0; j < 32; ++j) {       // 32 independent nt loads, tiny state
        nf4 v = __builtin_nontemporal_load(&base[(size_t)j * 8 * 192]);
        acc += v;
    }

    // Epilogue (proven ~free by R4 ablation): 192 f4 -> 24 classes -> 8 sums.
    __shared__ float4 arr[192];
    __shared__ float4 arr2[48];
    __shared__ float  cls[24];

    arr[t].x = acc.x; arr[t].y = acc.y; arr[t].z = acc.z; arr[t].w = acc.w;
    __syncthreads();

    if (t < 48) {      // fold stride-48 groups: (4(t+48g)+e)%24 == (4t+e)%24
        float4 a0 = arr[t], a1 = arr[t + 48], a2 = arr[t + 96], a3 = arr[t + 144];
        float4 s;
        s.x = a0.x + a1.x + a2.x + a3.x;
        s.y = a0.y + a1.y + a2.y + a3.y;
        s.z = a0.z + a1.z + a2.z + a3.z;
        s.w = a0.w + a1.w + a2.w + a3.w;
        arr2[t] = s;
    }
    __syncthreads();

    if (t < 6) {       // fold stride-6 groups: class m = 4t+e, m in [0,24)
        float4 s; s.x = s.y = s.z = s.w = 0.f;
#pragma unroll
        for (int g = 0; g < 8; ++g) {
            float4 v = arr2[t + 6 * g];
            s.x += v.x; s.y += v.y; s.z += v.z; s.w += v.w;
        }
        cls[4 * t + 0] = s.x;
        cls[4 * t + 1] = s.y;
        cls[4 * t + 2] = s.z;
        cls[4 * t + 3] = s.w;
    }
    __syncthreads();

    if (t < 8) {       // class m = 3w + c: sum channels -> S_x[b, h*8+w]
        sxf[b * 64 + h * 8 + t] = cls[3 * t] + cls[3 * t + 1] + cls[3 * t + 2];
    }
}

// K2: collapse C partials once. 6 blocks x 192 threads cover 1024 cols.
__global__ __launch_bounds__(192) void collapse_C(
    const float* __restrict__ cpart,   // [96][1024]
    float* __restrict__ scf)           // [1024]
{
    const int col = blockIdx.x * 192 + threadIdx.x;
    if (col < 1024) {
        float s = 0.f;
#pragma unroll 8
        for (int g = 0; g < 96; ++g) s += cpart[g * 1024 + col];
        scf[col] = s;
    }
}

// K3: pure expand. grid (8, 128): block = (kl-chunk of 128, image b).
// Per block: 192 broadcast floats in, 2048 nontemporal float4 stores out.
__global__ __launch_bounds__(256) void expand_out(
    const float* __restrict__ sxf,    // [128][64]
    const float* __restrict__ scf,    // [1024]
    float4* __restrict__ out4)        // [128][1024][16]
{
    const int t   = threadIdx.x;
    const int klc = blockIdx.x;   // [0,8)
    const int b   = blockIdx.y;   // [0,128)

    __shared__ float4 sxv[16];    // sx[b][0..63] as 16 f4
    __shared__ float  scl[128];   // sC[klc*128 .. +128]

    if (t < 16) {
        sxv[t] = ((const float4*)(sxf + b * 64))[t];
    } else if (t >= 64 && t < 192) {
        scl[t - 64] = scf[klc * 128 + (t - 64)];
    }
    __syncthreads();

    float4* ob = out4 + (size_t)b * 16384 + (size_t)klc * 2048;
#pragma unroll
    for (int k = 0; k < 8; ++k) {
        const int idx = k * 256 + t;        // [0,2048)
        const float4 v = sxv[idx & 15];     // LDS broadcast
        const float  s = scl[idx >> 4];
        nf4 r;
        r.x = v.x * s; r.y = v.y * s; r.z = v.z * s; r.w = v.w * s;
        __builtin_nontemporal_store(r, (nf4*)&ob[idx]);
    }
}

extern "C" void kernel_launch(void* const* d_in, const int* in_sizes, int n_in,
                              void* d_out, int out_size, void* d_ws, size_t ws_size,
                              hipStream_t stream) {
    const float4* x4 = (const float4*)d_in[0];   // 128*256*256*3 floats
    const float4* C4 = (const float4*)d_in[1];   // 3072*1024 floats

    float* cpart = (float*)d_ws;                  // 96*1024 floats
    float* sxf   = cpart + 96 * 1024;             // 128*64 floats
    float* scf   = sxf + 128 * 64;                // 1024 floats

    reduce_partials<<<dim3(1024 + 96), 192, 0, stream>>>(x4, C4, cpart, sxf);
    collapse_C<<<dim3(6),              192, 0, stream>>>(cpart, scf);
    expand_out<<<dim3(8, 128),         256, 0, stream>>>(sxf, scf, (float4*)d_out);
}